// Round 8
// baseline (129.383 us; speedup 1.0000x reference)
//
#include <hip/hip_runtime.h>
#include <hip/hip_bf16.h>
#include <stdint.h>
#include <float.h>

// ItemEncoder: h = relu(concat(emb[type], item) @ W + b); out = max over item axis.
// BS=32, NA=128, NI=128, F=11, TH=32, K=43 (pad->48), NH=128.
//
// R8: MEASUREMENT ROUND. Kernel identical to R7 (1-wave blocks, zero LDS/barriers).
// item_encoder launched 3x (idempotent, graph-safe): dur_us delta vs R7's single
// launch = 2x kernel_time + ~2 launch gaps. Discriminates H1 (kernel ~30 us,
// structure-invariant stall) from H2 (kernel ~10 us, harness-floor dominated).
//  - prep_b unchanged: W -> f16 MFMA B-fragments in d_ws (12 KB), coalesced.

#define NITEM  128
#define NFEAT  11
#define NTH    32
#define NH     128
#define KREAL  43
#define KSTEPS 3            // K = 48 = 3 x 16
#define SLABDW (NITEM * NFEAT)   // 1408 dwords per bn

typedef __attribute__((ext_vector_type(8)))  _Float16 half8;
typedef __attribute__((ext_vector_type(2)))  __fp16   fp16x2;   // cvt_pkrtz result type
typedef __attribute__((ext_vector_type(16))) float    f32x16;

union H8 { half8 h8; fp16x2 h2[4]; };

// ---- pre-kernel: build B fragments (frag = kk*4+n, 64 lanes each, half8/lane) ----
__global__ __launch_bounds__(64) void prep_b(const float* __restrict__ W,
                                             _Float16* __restrict__ Bpre) {
    const int frag = blockIdx.x;          // 0..11 = kk*4 + n
    const int kk   = frag >> 2;
    const int n    = frag & 3;
    const int lane = threadIdx.x;         // 0..63
    const int col  = n * 32 + (lane & 31);
    const int k0   = kk * 16 + (lane >> 5) * 8;
    half8 pk;
    #pragma unroll
    for (int q = 0; q < 8; ++q) {
        const int k = k0 + q;
        pk[q] = (_Float16)((k < KREAL) ? W[k * NH + col] : 0.0f);
    }
    ((half8*)Bpre)[frag * 64 + lane] = pk;
}

__global__ __launch_bounds__(64, 2) void item_encoder(
    const int*      __restrict__ item_type,  // [BS*NA*NI] int32
    const float*    __restrict__ item,       // [BS*NA*NI*NFEAT]
    const float*    __restrict__ emb,        // [18*32]
    const _Float16* __restrict__ Bpre,       // [12*64*8] f16 frags
    const float*    __restrict__ bias,       // [128]
    float*          __restrict__ out)        // [BS*NA*NH]
{
    const int lane = threadIdx.x;            // 0..63 (one wave per block)
    const int l31  = lane & 31;
    const int lhi  = lane >> 5;              // k-half selector
    const int bn   = blockIdx.x;             // 0..4095

    // ---- B fragments: 12 coalesced 16B loads/lane (L2-resident after first waves) ----
    half8 bf[KSTEPS][4];
    #pragma unroll
    for (int kk = 0; kk < KSTEPS; ++kk)
        #pragma unroll
        for (int n = 0; n < 4; ++n)
            bf[kk][n] = ((const half8*)Bpre)[(kk * 4 + n) * 64 + lane];

    // ---- ty for this wave's 4 row-blocks (lanes 32-63 mirror 0-31: broadcast) ----
    int ty[4];
    {
        const int* tb = item_type + (size_t)bn * NITEM + l31;
        #pragma unroll
        for (int rb = 0; rb < 4; ++rb) ty[rb] = tb[rb * 32];
    }

    float bias4[4];
    #pragma unroll
    for (int n = 0; n < 4; ++n) bias4[n] = bias[n * 32 + l31];

    const float* feat = item + (size_t)bn * SLABDW;

    float vm[4] = { -FLT_MAX, -FLT_MAX, -FLT_MAX, -FLT_MAX };

    // ---- 4 row-blocks, fully unrolled; each: 12 loads -> cvt -> 12 MFMA -> max ----
    #pragma unroll
    for (int rb = 0; rb < 4; ++rb) {
        const int r = rb * 32 + l31;         // this lane's item row

        // emb slices for a0 (k=0..15) and a1 (k=16..31): aligned float4s
        const float* eb = emb + ty[rb] * NTH + lhi * 8;
        const float4 e0 = *(const float4*)(eb);
        const float4 e1 = *(const float4*)(eb + 4);
        const float4 e2 = *(const float4*)(eb + 16);
        const float4 e3 = *(const float4*)(eb + 20);

        // feats straight from global, lane-sliced: lhi=0 -> f=0..7; lhi=1 -> f=8..10,+pad
        const float* fp = feat + r * NFEAT;
        float fv[8];
        #pragma unroll
        for (int q = 0; q < 8; ++q) {
            const int  f    = lhi ? ((q < 3) ? 8 + q : 10) : q;   // clamp addr in-row
            const bool dead = (lhi && q >= 3);
            const float x = fp[f];
            fv[q] = dead ? 0.0f : x;
        }

        H8 a0, a1, a2;
        a0.h2[0] = __builtin_amdgcn_cvt_pkrtz(e0.x, e0.y);
        a0.h2[1] = __builtin_amdgcn_cvt_pkrtz(e0.z, e0.w);
        a0.h2[2] = __builtin_amdgcn_cvt_pkrtz(e1.x, e1.y);
        a0.h2[3] = __builtin_amdgcn_cvt_pkrtz(e1.z, e1.w);
        a1.h2[0] = __builtin_amdgcn_cvt_pkrtz(e2.x, e2.y);
        a1.h2[1] = __builtin_amdgcn_cvt_pkrtz(e2.z, e2.w);
        a1.h2[2] = __builtin_amdgcn_cvt_pkrtz(e3.x, e3.y);
        a1.h2[3] = __builtin_amdgcn_cvt_pkrtz(e3.z, e3.w);
        a2.h2[0] = __builtin_amdgcn_cvt_pkrtz(fv[0], fv[1]);
        a2.h2[1] = __builtin_amdgcn_cvt_pkrtz(fv[2], fv[3]);
        a2.h2[2] = __builtin_amdgcn_cvt_pkrtz(fv[4], fv[5]);
        a2.h2[3] = __builtin_amdgcn_cvt_pkrtz(fv[6], fv[7]);

        f32x16 acc[4];
        #pragma unroll
        for (int n = 0; n < 4; ++n)
            #pragma unroll
            for (int rr = 0; rr < 16; ++rr) acc[n][rr] = 0.0f;

        #pragma unroll
        for (int n = 0; n < 4; ++n) acc[n] = __builtin_amdgcn_mfma_f32_32x32x16_f16(a0.h8, bf[0][n], acc[n], 0, 0, 0);
        #pragma unroll
        for (int n = 0; n < 4; ++n) acc[n] = __builtin_amdgcn_mfma_f32_32x32x16_f16(a1.h8, bf[1][n], acc[n], 0, 0, 0);
        #pragma unroll
        for (int n = 0; n < 4; ++n) acc[n] = __builtin_amdgcn_mfma_f32_32x32x16_f16(a2.h8, bf[2][n], acc[n], 0, 0, 0);

        // max over this row-block's 32 rows, fold into running col-max
        // C/D layout: col = lane&31, row = (reg&3) + 8*(reg>>2) + 4*(lane>>5)
        #pragma unroll
        for (int n = 0; n < 4; ++n) {
            float m = acc[n][0];
            #pragma unroll
            for (int rr = 1; rr < 16; ++rr) m = fmaxf(m, acc[n][rr]);
            m = fmaxf(m, __shfl_xor(m, 32));     // fold the two 16-row halves
            vm[n] = fmaxf(vm[n], m);
        }
    }

    // ---- store: lanes 0..31 hold the 128-col result for this bn ----
    if (lane < 32) {
        #pragma unroll
        for (int n = 0; n < 4; ++n)
            out[(size_t)bn * NH + n * 32 + l31] = fmaxf(vm[n] + bias4[n], 0.0f);
    }
}

extern "C" void kernel_launch(void* const* d_in, const int* in_sizes, int n_in,
                              void* d_out, int out_size, void* d_ws, size_t ws_size,
                              hipStream_t stream) {
    const int*   item_type = (const int*)  d_in[0];
    const float* item      = (const float*)d_in[1];
    const float* emb       = (const float*)d_in[2];
    const float* W         = (const float*)d_in[3];
    const float* bias      = (const float*)d_in[4];
    float*       out       = (float*)d_out;
    _Float16*    Bpre      = (_Float16*)d_ws;   // 12*64*8*2 = 12 KB

    prep_b<<<12, 64, 0, stream>>>(W, Bpre);
    // 3x idempotent launches: dur_us delta vs R7 = 2x kernel time (measurement probe)
    item_encoder<<<32 * 128, 64, 0, stream>>>(item_type, item, emb, Bpre, bias, out);
    item_encoder<<<32 * 128, 64, 0, stream>>>(item_type, item, emb, Bpre, bias, out);
    item_encoder<<<32 * 128, 64, 0, stream>>>(item_type, item, emb, Bpre, bias, out);
}

// Round 9
// 88.115 us; speedup vs baseline: 1.4683x; 1.4683x over previous
//
#include <hip/hip_runtime.h>
#include <hip/hip_bf16.h>
#include <stdint.h>
#include <float.h>

// ItemEncoder: h = relu(concat(emb[type], item) @ W + b); out = max over item axis.
// BS=32, NA=128, NI=128, F=11, TH=32, K=43 (pad->48), NH=128.
//
// R9: occupancy attack (R8 measured kernel ~17.7 us vs ~6 us issue model; est.
// VGPR ~200 -> 2 waves/SIMD). Shrink per-wave footprint to hit 4 waves/SIMD:
//  - 2 waves per bn, split by output cols: wave w -> cols [w*64, w*64+64).
//    acc 64->32 VGPR, bf 48->24. Row-max stays in-wave; disjoint col stores.
//  - emb pre-converted to f16 in prep kernel -> a0/a1 are direct half8 loads
//    (kills 16 cvt/wave, halves E-space).
//  - feats staged once per block into LDS (3 coalesced float4 rounds, 2 waves
//    share); fv reads stride-11 LDS = conflict-free (gcd(11,32)=1).
//  - prep: W -> f16 B-fragments + emb -> f16, both in d_ws.

#define NITEM  128
#define NFEAT  11
#define NTH    32
#define NH     128
#define KREAL  43
#define KSTEPS 3            // K = 48 = 3 x 16
#define SLABDW (NITEM * NFEAT)   // 1408 dwords per bn
#define EMBOFF (12 * 1024)       // byte offset of f16 emb table in d_ws

typedef __attribute__((ext_vector_type(8)))  _Float16 half8;
typedef __attribute__((ext_vector_type(2)))  __fp16   fp16x2;   // cvt_pkrtz result type
typedef __attribute__((ext_vector_type(16))) float    f32x16;

union H8 { half8 h8; fp16x2 h2[4]; };

// ---- pre-kernel: blocks 0..11 build B fragments; block 12 converts emb to f16 ----
__global__ __launch_bounds__(64) void prep(const float* __restrict__ W,
                                           const float* __restrict__ emb,
                                           _Float16* __restrict__ ws) {
    const int blk  = blockIdx.x;
    const int lane = threadIdx.x;         // 0..63
    if (blk < 12) {                       // B frag: frag = kk*4 + n
        const int kk  = blk >> 2;
        const int n   = blk & 3;
        const int col = n * 32 + (lane & 31);
        const int k0  = kk * 16 + (lane >> 5) * 8;
        half8 pk;
        #pragma unroll
        for (int q = 0; q < 8; ++q) {
            const int k = k0 + q;
            pk[q] = (_Float16)((k < KREAL) ? W[k * NH + col] : 0.0f);
        }
        ((half8*)ws)[blk * 64 + lane] = pk;
    } else {                              // emb: 18*32 = 576 f32 -> f16
        _Float16* eh = ws + EMBOFF / 2;
        #pragma unroll
        for (int j = 0; j < 9; ++j) {
            const int idx = j * 64 + lane;            // 0..575
            eh[idx] = (_Float16)emb[idx];
        }
    }
}

__global__ __launch_bounds__(128, 4) void item_encoder(
    const int*      __restrict__ item_type,  // [BS*NA*NI] int32
    const float*    __restrict__ item,       // [BS*NA*NI*NFEAT]
    const _Float16* __restrict__ ws,         // B frags (12 KB) + f16 emb (1.2 KB)
    const float*    __restrict__ bias,       // [128]
    float*          __restrict__ out)        // [BS*NA*NH]
{
    __shared__ float slab[SLABDW];           // 5632 B, this bn's raw f32 feats

    const int t    = threadIdx.x;            // 0..127 (2 waves)
    const int lane = t & 63;
    const int w    = t >> 6;                 // wave = col-half selector
    const int l31  = lane & 31;
    const int lhi  = lane >> 5;              // k-half selector
    const int bn   = blockIdx.x;             // 0..4095

    // ---- stage this bn's feats into LDS: 3 coalesced float4 rounds ----
    {
        const float4* gsl = (const float4*)(item + (size_t)bn * SLABDW);
        float4*       lsl = (float4*)slab;
        lsl[t]       = gsl[t];               // 0..127
        lsl[t + 128] = gsl[t + 128];         // 128..255
        if (t < 96) lsl[t + 256] = gsl[t + 256];   // 256..351
    }

    // ---- ty for the 4 row-blocks (independent of LDS; issue before barrier) ----
    int ty[4];
    {
        const int* tb = item_type + (size_t)bn * NITEM + l31;
        #pragma unroll
        for (int rb = 0; rb < 4; ++rb) ty[rb] = tb[rb * 32];
    }

    // ---- B fragments for this wave's col-half: 6 coalesced 16B loads ----
    // global n = w*2 + n2, frag index = kk*4 + n
    half8 bf[KSTEPS][2];
    #pragma unroll
    for (int kk = 0; kk < KSTEPS; ++kk)
        #pragma unroll
        for (int n2 = 0; n2 < 2; ++n2)
            bf[kk][n2] = ((const half8*)ws)[(kk * 4 + (w * 2 + n2)) * 64 + lane];

    // ---- emb f16 frags for all 4 row-blocks (direct half8, no cvt) ----
    const _Float16* eh = ws + EMBOFF / 2;
    half8 ea0[4], ea1[4];
    #pragma unroll
    for (int rb = 0; rb < 4; ++rb) {
        const _Float16* eb = eh + ty[rb] * NTH + lhi * 8;
        ea0[rb] = *(const half8*)(eb);
        ea1[rb] = *(const half8*)(eb + 16);
    }

    float bias2[2];
    #pragma unroll
    for (int n2 = 0; n2 < 2; ++n2) bias2[n2] = bias[(w * 2 + n2) * 32 + l31];

    __syncthreads();

    float vm[2] = { -FLT_MAX, -FLT_MAX };

    // ---- 4 row-blocks: fv from LDS, cvt, 6 MFMA each, fold max ----
    #pragma unroll
    for (int rb = 0; rb < 4; ++rb) {
        const int r = rb * 32 + l31;         // this lane's item row

        // feats f: lhi=0 -> 0..7; lhi=1 -> 8..10 + pad (stride-11 LDS, <=2-way)
        const float* sp = slab + r * NFEAT;
        float fv[8];
        #pragma unroll
        for (int q = 0; q < 8; ++q) {
            const int  f    = lhi ? ((q < 3) ? 8 + q : 10) : q;
            const bool dead = (lhi && q >= 3);
            const float x = sp[f];
            fv[q] = dead ? 0.0f : x;
        }

        H8 a2;
        a2.h2[0] = __builtin_amdgcn_cvt_pkrtz(fv[0], fv[1]);
        a2.h2[1] = __builtin_amdgcn_cvt_pkrtz(fv[2], fv[3]);
        a2.h2[2] = __builtin_amdgcn_cvt_pkrtz(fv[4], fv[5]);
        a2.h2[3] = __builtin_amdgcn_cvt_pkrtz(fv[6], fv[7]);

        f32x16 acc[2];
        #pragma unroll
        for (int n2 = 0; n2 < 2; ++n2)
            #pragma unroll
            for (int rr = 0; rr < 16; ++rr) acc[n2][rr] = 0.0f;

        #pragma unroll
        for (int n2 = 0; n2 < 2; ++n2) acc[n2] = __builtin_amdgcn_mfma_f32_32x32x16_f16(ea0[rb], bf[0][n2], acc[n2], 0, 0, 0);
        #pragma unroll
        for (int n2 = 0; n2 < 2; ++n2) acc[n2] = __builtin_amdgcn_mfma_f32_32x32x16_f16(ea1[rb], bf[1][n2], acc[n2], 0, 0, 0);
        #pragma unroll
        for (int n2 = 0; n2 < 2; ++n2) acc[n2] = __builtin_amdgcn_mfma_f32_32x32x16_f16(a2.h8,   bf[2][n2], acc[n2], 0, 0, 0);

        // max over this row-block's 32 rows, fold into running col-max
        // C/D layout: col = lane&31, row = (reg&3) + 8*(reg>>2) + 4*(lane>>5)
        #pragma unroll
        for (int n2 = 0; n2 < 2; ++n2) {
            float m = acc[n2][0];
            #pragma unroll
            for (int rr = 1; rr < 16; ++rr) m = fmaxf(m, acc[n2][rr]);
            m = fmaxf(m, __shfl_xor(m, 32)); // fold the two 16-row halves
            vm[n2] = fmaxf(vm[n2], m);
        }
    }

    // ---- store: lanes 0..31 of wave w write cols [w*64, w*64+64) ----
    if (lane < 32) {
        #pragma unroll
        for (int n2 = 0; n2 < 2; ++n2)
            out[(size_t)bn * NH + (w * 2 + n2) * 32 + l31] =
                fmaxf(vm[n2] + bias2[n2], 0.0f);
    }
}

extern "C" void kernel_launch(void* const* d_in, const int* in_sizes, int n_in,
                              void* d_out, int out_size, void* d_ws, size_t ws_size,
                              hipStream_t stream) {
    const int*   item_type = (const int*)  d_in[0];
    const float* item      = (const float*)d_in[1];
    const float* emb       = (const float*)d_in[2];
    const float* W         = (const float*)d_in[3];
    const float* bias      = (const float*)d_in[4];
    float*       out       = (float*)d_out;
    _Float16*    ws        = (_Float16*)d_ws;   // 12 KB B-frags + 1.2 KB f16 emb

    prep<<<13, 64, 0, stream>>>(W, emb, ws);
    item_encoder<<<32 * 128, 128, 0, stream>>>(item_type, item, ws, bias, out);
}

// Round 10
// 85.413 us; speedup vs baseline: 1.5148x; 1.0316x over previous
//
#include <hip/hip_runtime.h>
#include <hip/hip_bf16.h>
#include <stdint.h>
#include <float.h>

// ItemEncoder: h = relu(concat(emb[type], item) @ W + b); out = max over item axis.
// BS=32, NA=128, NI=128, F=11, TH=32, K=43 (pad->48), NH=128.
//
// R10: single fused kernel — prep pass + d_ws dependency removed (was ~4-5 us of
// dispatch + graph-drain serialization). Per block (one bn, 2 waves, col-split):
//  - B-frags built in-wave from W via coalesced row-segment loads (lanes 0-31 =
//    contiguous 128B of row k; L1/L2-resident 22 KB) + cvt_pkrtz. 48 loads/wave.
//  - emb converted once per block into an LDS f16 table, rows padded to 40 f16
//    (80 B) so ty-gather ds_read_b128 spreads over 8 bank-groups.
//  - feats staged once per block into LDS (3 coalesced float4 rounds);
//    fv reads stride-11 = conflict-free.
//  - 24 MFMA/wave (32x32x16_f16), row-max in-wave, disjoint col-half stores.

#define NITEM  128
#define NFEAT  11
#define NTH    32
#define NH     128
#define KREAL  43
#define KSTEPS 3            // K = 48 = 3 x 16
#define SLABDW (NITEM * NFEAT)   // 1408 dwords per bn
#define ESTRIDE 40          // f16 elems per emb row in LDS (80 B, 16B-aligned)

typedef __attribute__((ext_vector_type(8)))  _Float16 half8;
typedef __attribute__((ext_vector_type(2)))  __fp16   fp16x2;   // cvt_pkrtz result type
typedef __attribute__((ext_vector_type(16))) float    f32x16;

union H8 { half8 h8; fp16x2 h2[4]; };

__global__ __launch_bounds__(128, 4) void item_encoder(
    const int*   __restrict__ item_type,  // [BS*NA*NI] int32
    const float* __restrict__ item,       // [BS*NA*NI*NFEAT]
    const float* __restrict__ emb,        // [18*32] f32
    const float* __restrict__ W,          // [43*128] f32
    const float* __restrict__ bias,       // [128]
    float*       __restrict__ out)        // [BS*NA*NH]
{
    __shared__ float    slab[SLABDW];            // 5632 B, this bn's raw f32 feats
    __shared__ _Float16 ehl[18 * ESTRIDE];       // 1440 B, f16 emb, stride-40 rows

    const int t    = threadIdx.x;            // 0..127 (2 waves)
    const int lane = t & 63;
    const int w    = t >> 6;                 // wave = col-half selector
    const int l31  = lane & 31;
    const int lhi  = lane >> 5;              // k-half selector
    const int bn   = blockIdx.x;             // 0..4095

    // ---- stage this bn's feats into LDS: 3 coalesced float4 rounds ----
    {
        const float4* gsl = (const float4*)(item + (size_t)bn * SLABDW);
        float4*       lsl = (float4*)slab;
        lsl[t]       = gsl[t];               // 0..127
        lsl[t + 128] = gsl[t + 128];         // 128..255
        if (t < 96) lsl[t + 256] = gsl[t + 256];   // 256..351
    }

    // ---- stage emb into LDS as f16 (576 vals, coalesced reads, stride-40 rows) ----
    #pragma unroll
    for (int j = 0; j < 5; ++j) {
        const int idx = t + 128 * j;         // 0..639
        if (idx < 18 * NTH) {
            const int ety = idx >> 5;        // 0..17
            const int ec  = idx & 31;
            ehl[ety * ESTRIDE + ec] = (_Float16)emb[idx];
        }
    }

    // ---- ty for the 4 row-blocks (independent; issue before barrier) ----
    int ty[4];
    {
        const int* tb = item_type + (size_t)bn * NITEM + l31;
        #pragma unroll
        for (int rb = 0; rb < 4; ++rb) ty[rb] = tb[rb * 32];
    }

    // ---- B-frags from W, in-wave: lanes 0-31 read contiguous 128B row segments ----
    // frag (kk,n2): need W[k][col], k = kk*16 + lhi*8 + q, col = (w*2+n2)*32 + l31
    half8 bf[KSTEPS][2];
    #pragma unroll
    for (int kk = 0; kk < KSTEPS; ++kk) {
        #pragma unroll
        for (int n2 = 0; n2 < 2; ++n2) {
            const int col = (w * 2 + n2) * 32 + l31;
            const float* wb = W + (kk * 16 + lhi * 8) * NH + col;
            H8 pk;
            #pragma unroll
            for (int qq = 0; qq < 4; ++qq) {
                const int k0 = kk * 16 + lhi * 8 + 2 * qq;
                const int k1 = k0 + 1;
                const float x0 = (k0 < KREAL) ? wb[(2 * qq)     * NH] : 0.0f;
                const float x1 = (k1 < KREAL) ? wb[(2 * qq + 1) * NH] : 0.0f;
                pk.h2[qq] = __builtin_amdgcn_cvt_pkrtz(x0, x1);
            }
            bf[kk][n2] = pk.h8;
        }
    }

    float bias2[2];
    #pragma unroll
    for (int n2 = 0; n2 < 2; ++n2) bias2[n2] = bias[(w * 2 + n2) * 32 + l31];

    __syncthreads();

    // ---- emb f16 frags for the 4 row-blocks: 8x ds_read_b128 (stride-40 rows) ----
    half8 ea0[4], ea1[4];
    #pragma unroll
    for (int rb = 0; rb < 4; ++rb) {
        const _Float16* eb = ehl + ty[rb] * ESTRIDE + lhi * 8;
        ea0[rb] = *(const half8*)(eb);
        ea1[rb] = *(const half8*)(eb + 16);
    }

    float vm[2] = { -FLT_MAX, -FLT_MAX };

    // ---- 4 row-blocks: fv from LDS, cvt, 6 MFMA each, fold max ----
    #pragma unroll
    for (int rb = 0; rb < 4; ++rb) {
        const int r = rb * 32 + l31;         // this lane's item row

        // feats f: lhi=0 -> 0..7; lhi=1 -> 8..10 + pad (stride-11 LDS, <=2-way)
        const float* sp = slab + r * NFEAT;
        float fv[8];
        #pragma unroll
        for (int q = 0; q < 8; ++q) {
            const int  f    = lhi ? ((q < 3) ? 8 + q : 10) : q;
            const bool dead = (lhi && q >= 3);
            const float x = sp[f];
            fv[q] = dead ? 0.0f : x;
        }

        H8 a2;
        a2.h2[0] = __builtin_amdgcn_cvt_pkrtz(fv[0], fv[1]);
        a2.h2[1] = __builtin_amdgcn_cvt_pkrtz(fv[2], fv[3]);
        a2.h2[2] = __builtin_amdgcn_cvt_pkrtz(fv[4], fv[5]);
        a2.h2[3] = __builtin_amdgcn_cvt_pkrtz(fv[6], fv[7]);

        f32x16 acc[2];
        #pragma unroll
        for (int n2 = 0; n2 < 2; ++n2)
            #pragma unroll
            for (int rr = 0; rr < 16; ++rr) acc[n2][rr] = 0.0f;

        #pragma unroll
        for (int n2 = 0; n2 < 2; ++n2) acc[n2] = __builtin_amdgcn_mfma_f32_32x32x16_f16(ea0[rb], bf[0][n2], acc[n2], 0, 0, 0);
        #pragma unroll
        for (int n2 = 0; n2 < 2; ++n2) acc[n2] = __builtin_amdgcn_mfma_f32_32x32x16_f16(ea1[rb], bf[1][n2], acc[n2], 0, 0, 0);
        #pragma unroll
        for (int n2 = 0; n2 < 2; ++n2) acc[n2] = __builtin_amdgcn_mfma_f32_32x32x16_f16(a2.h8,   bf[2][n2], acc[n2], 0, 0, 0);

        // max over this row-block's 32 rows, fold into running col-max
        // C/D layout: col = lane&31, row = (reg&3) + 8*(reg>>2) + 4*(lane>>5)
        #pragma unroll
        for (int n2 = 0; n2 < 2; ++n2) {
            float m = acc[n2][0];
            #pragma unroll
            for (int rr = 1; rr < 16; ++rr) m = fmaxf(m, acc[n2][rr]);
            m = fmaxf(m, __shfl_xor(m, 32)); // fold the two 16-row halves
            vm[n2] = fmaxf(vm[n2], m);
        }
    }

    // ---- store: lanes 0..31 of wave w write cols [w*64, w*64+64) ----
    if (lane < 32) {
        #pragma unroll
        for (int n2 = 0; n2 < 2; ++n2)
            out[(size_t)bn * NH + (w * 2 + n2) * 32 + l31] =
                fmaxf(vm[n2] + bias2[n2], 0.0f);
    }
}

extern "C" void kernel_launch(void* const* d_in, const int* in_sizes, int n_in,
                              void* d_out, int out_size, void* d_ws, size_t ws_size,
                              hipStream_t stream) {
    const int*   item_type = (const int*)  d_in[0];
    const float* item      = (const float*)d_in[1];
    const float* emb       = (const float*)d_in[2];
    const float* W         = (const float*)d_in[3];
    const float* bias      = (const float*)d_in[4];
    float*       out       = (float*)d_out;

    item_encoder<<<32 * 128, 128, 0, stream>>>(item_type, item, emb, W, bias, out);
}